// Round 1
// baseline (4030.801 us; speedup 1.0000x reference)
//
#include <hip/hip_runtime.h>
#include <cmath>

// Problem constants (from reference)
constexpr int K_H   = 4096;    // hidden
constexpr int V_N   = 32000;   // vocab
constexpr int M_TOK = 4096;    // 8 * 512 tokens
constexpr int T_SEQ = 512;
constexpr int NPAIRS = 4;
constexpr float BETA = 0.1f;
constexpr int IGNORE_IDX = -100;   // target arrives as int32 from the harness

constexpr int NBLK_F = V_N / 128;  // 250 n-tiles (fp32 fallback)
constexpr int NBLK_M = V_N / 256;  // 125 n-tiles (mfma path)

typedef _Float16 h8 __attribute__((ext_vector_type(8)));
typedef _Float16 h4 __attribute__((ext_vector_type(4)));
typedef float    f4 __attribute__((ext_vector_type(4)));

// ---------------------------------------------------------------------------
// async global->LDS 16B (wave-uniform LDS base + lane*16)
// ---------------------------------------------------------------------------
__device__ __forceinline__ void async_copy16(void* lds, const void* g) {
    __builtin_amdgcn_global_load_lds(
        (const __attribute__((address_space(1))) unsigned int*)g,
        (__attribute__((address_space(3))) unsigned int*)lds, 16, 0, 0);
}

__device__ __forceinline__ f4 mf(h8 a, h8 b, f4 c) {
    return __builtin_amdgcn_mfma_f32_16x16x32_f16(a, b, c, 0, 0, 0);
}

// ---------------------------------------------------------------------------
// fp32 -> (f16 hi, f16 lo) plane conversion, float4-vectorized
// ---------------------------------------------------------------------------
__global__ __launch_bounds__(256)
void convert_kernel(const float* __restrict__ src, _Float16* __restrict__ hi,
                    _Float16* __restrict__ lo, int n4)
{
    const int i = blockIdx.x * 256 + threadIdx.x;
    if (i >= n4) return;
    const float4 v = ((const float4*)src)[i];
    h4 h, l;
    h.x = (_Float16)v.x; l.x = (_Float16)(v.x - (float)h.x);
    h.y = (_Float16)v.y; l.y = (_Float16)(v.y - (float)h.y);
    h.z = (_Float16)v.z; l.z = (_Float16)(v.z - (float)h.z);
    h.w = (_Float16)v.w; l.w = (_Float16)(v.w - (float)h.w);
    ((h4*)hi)[i] = h;
    ((h4*)lo)[i] = l;
}

// ---------------------------------------------------------------------------
// 256x256-tile split-f16 MFMA GEMM + fused per-row max / sum(exp).
// 8 waves (2M x 4N), BK=32, 4 LDS planes (Ah,Al,Bh,Bl), double-buffered
// (2 x 64 KB). Phased schedule (4 phases / K-tile) with counted vmcnt:
// tile t+2's loads are issued mid-body and stay in flight across all
// barriers; s_waitcnt vmcnt(8) at body end waits only for tile t+1.
//
// LDS layout per plane: 128 lines x 128 B. Line L holds rows {2L, 2L+1},
// each 4 octets (16 B). Slot s of line L stores s' = s ^ (L&7), with
// s' = (rowparity<<2)|octet -> every 16-lane ds_read_b128 group maps
// 2 lanes per 16B slot (conflict-free). global_load_lds writes linearly;
// the per-lane GLOBAL source carries the inverse swizzle.
//
// acc += Ah*Bh + Ah*Bl + Al*Bh  (xl*wl dropped: <=2^-22 rel per product).
// Accumulation order over K identical to the previous passing kernel.
// ---------------------------------------------------------------------------
template <int MIA, int MIB>
__device__ __forceinline__
void phase_mfma(f4 (&acc)[8][4], const h8 (&bhf)[4], const h8 (&blf)[4],
                const _Float16* PAh, const _Float16* PAl, int aoffA, int aoffB)
{
    h8 ah0 = *(const h8*)&PAh[aoffA];
    h8 al0 = *(const h8*)&PAl[aoffA];
    h8 ah1 = *(const h8*)&PAh[aoffB];
    h8 al1 = *(const h8*)&PAl[aoffB];
    __builtin_amdgcn_s_barrier();
    asm volatile("s_waitcnt lgkmcnt(0)" ::: "memory");
    __builtin_amdgcn_sched_barrier(0);
    __builtin_amdgcn_s_setprio(1);
#pragma unroll
    for (int nj = 0; nj < 4; ++nj) {
        acc[MIA][nj] = mf(ah0, bhf[nj], acc[MIA][nj]);
        acc[MIA][nj] = mf(ah0, blf[nj], acc[MIA][nj]);
        acc[MIA][nj] = mf(al0, bhf[nj], acc[MIA][nj]);
        acc[MIB][nj] = mf(ah1, bhf[nj], acc[MIB][nj]);
        acc[MIB][nj] = mf(ah1, blf[nj], acc[MIB][nj]);
        acc[MIB][nj] = mf(al1, bhf[nj], acc[MIB][nj]);
    }
    __builtin_amdgcn_s_setprio(0);
    __builtin_amdgcn_s_barrier();
    asm volatile("" ::: "memory");
}

// staging: wave w instr i covers LDS halves [1024w+512i, +512) of a plane,
// lane l -> +8l. Source: line = 16w+8i+(l>>3); s' = (l&7)^(l>>3);
// row = 2*line + (s'>>2); octet = s'&3.
#define STAGE_A_(BUF, KTN) do { \
    async_copy16(&LB[BUF][0][dst0],       bAh + (KTN)); \
    async_copy16(&LB[BUF][0][dst0 + 512], bAh + (KTN) + 16 * K_H); \
    async_copy16(&LB[BUF][1][dst0],       bAl + (KTN)); \
    async_copy16(&LB[BUF][1][dst0 + 512], bAl + (KTN) + 16 * K_H); \
} while (0)

#define STAGE_B_(BUF, KTN) do { \
    async_copy16(&LB[BUF][2][dst0],       bBh + (KTN)); \
    async_copy16(&LB[BUF][2][dst0 + 512], bBh + (KTN) + 16 * K_H); \
    async_copy16(&LB[BUF][3][dst0],       bBl + (KTN)); \
    async_copy16(&LB[BUF][3][dst0 + 512], bBl + (KTN) + 16 * K_H); \
} while (0)

// One K-tile body. STG/LAST are literal bools.
// stage_B(t+2) after phase 0 (B planes fully consumed into regs, globally
// barriered); stage_A(t+2) after phase 3 (all A reads barriered);
// vmcnt(8) = wait for tile t+1's 8 older loads only.
#define BODY(BUF, STG, KTN, LAST) do { \
    const _Float16* PAh = &LB[BUF][0][0]; \
    const _Float16* PAl = &LB[BUF][1][0]; \
    const _Float16* PBh = &LB[BUF][2][0]; \
    const _Float16* PBl = &LB[BUF][3][0]; \
    h8 bhf[4], blf[4]; \
    bhf[0] = *(const h8*)&PBh[boff0];        blf[0] = *(const h8*)&PBl[boff0]; \
    bhf[1] = *(const h8*)&PBh[boff0 + 512];  blf[1] = *(const h8*)&PBl[boff0 + 512]; \
    bhf[2] = *(const h8*)&PBh[boff0 + 1024]; blf[2] = *(const h8*)&PBl[boff0 + 1024]; \
    bhf[3] = *(const h8*)&PBh[boff0 + 1536]; blf[3] = *(const h8*)&PBl[boff0 + 1536]; \
    phase_mfma<0, 1>(acc, bhf, blf, PAh, PAl, aoff0, aoff0 + 512); \
    if (STG) STAGE_B_(BUF, KTN); \
    phase_mfma<2, 3>(acc, bhf, blf, PAh, PAl, aoff0 + 1024, aoff0 + 1536); \
    phase_mfma<4, 5>(acc, bhf, blf, PAh, PAl, aoff0 + 2048, aoff0 + 2560); \
    phase_mfma<6, 7>(acc, bhf, blf, PAh, PAl, aoff0 + 3072, aoff0 + 3584); \
    if (STG) { \
        STAGE_A_(BUF, KTN); \
        asm volatile("s_waitcnt vmcnt(8)" ::: "memory"); \
    } else if (!(LAST)) { \
        asm volatile("s_waitcnt vmcnt(0)" ::: "memory"); \
    } \
    if (!(LAST)) { \
        __builtin_amdgcn_s_barrier(); \
        asm volatile("" ::: "memory"); \
    } \
} while (0)

__global__ __launch_bounds__(512, 2)
void gemm_mfma_lse256(const _Float16* __restrict__ xh, const _Float16* __restrict__ xl,
                      const _Float16* __restrict__ wh, const _Float16* __restrict__ wl,
                      float* __restrict__ pmax, float* __restrict__ psum)
{
    __shared__ _Float16 LB[2][4][8192];   // [buf][plane][line*64 + slot*8]
    __shared__ float redm[4][256];
    __shared__ float reds[4][256];

    const int tid  = threadIdx.x;
    const int wave = tid >> 6;
    const int lane = tid & 63;
    const int g    = (lane >> 4) & 3;   // k-octet of fragment
    const int m16  = lane & 15;

    const int m0 = blockIdx.x * 256;    // m fastest in grid -> W tile reuse
    const int n0 = blockIdx.y * 256;
    const int wm = (wave >> 2) * 128;   // 2 m-wave groups
    const int wn = (wave & 3) * 64;     // 4 n-wave groups

    // ---- staging source geometry (per-lane, shared by all 4 planes) ----
    const int l8 = lane >> 3;
    const int sp = (lane & 7) ^ l8;     // s' = (e<<2)|o
    const int so = sp & 3;
    const int se = sp >> 2;
    const size_t laneoff = (size_t)(32 * wave + 2 * l8 + se) * K_H + so * 8;

    const _Float16* bAh = xh + (size_t)m0 * K_H + laneoff;
    const _Float16* bAl = xl + (size_t)m0 * K_H + laneoff;
    const _Float16* bBh = wh + (size_t)n0 * K_H + laneoff;
    const _Float16* bBl = wl + (size_t)n0 * K_H + laneoff;

    const int dst0 = 1024 * wave;       // LDS halves base (wave-uniform)

    // ---- fragment read offsets ----
    // addr(u,g) = (u>>1)*64 + ((((u&1)<<2)|g) ^ ((u>>1)&7))*8 ; u = base+mi*16+m16
    // base mult of 64 -> addr = const + mi*512, slot constant per thread.
    const int slot  = (((((m16 & 1) << 2) | g) ^ (m16 >> 1)) * 8);
    const int aoff0 = ((wm + m16) >> 1) * 64 + slot;
    const int boff0 = ((wn + m16) >> 1) * 64 + slot;

    f4 acc[8][4];
#pragma unroll
    for (int i = 0; i < 8; ++i)
#pragma unroll
        for (int j = 0; j < 4; ++j) acc[i][j] = (f4){0.f, 0.f, 0.f, 0.f};

    // ---- prologue: tiles 0 and 1 (8 loads each, in order) ----
    STAGE_A_(0, 0);  STAGE_B_(0, 0);
    STAGE_A_(1, 32); STAGE_B_(1, 32);
    asm volatile("s_waitcnt vmcnt(8)" ::: "memory");   // tile 0 landed
    __builtin_amdgcn_s_barrier();
    asm volatile("" ::: "memory");

    // ---- main loop: pairs (2i, 2i+1), staging tiles 2i+2, 2i+3 ----
#pragma clang loop unroll(disable)
    for (int kt = 0; kt < K_H - 64; kt += 64) {        // 63 iterations
        BODY(0, true, kt + 64, false);
        BODY(1, true, kt + 96, false);
    }
    BODY(0, false, 0, false);   // tile 126 (vmcnt(0): tile 127 landed)
    BODY(1, false, 0, true);    // tile 127

    // ---- epilogue: per-row (M) max & sum(exp) over this wave's 64 cols ----
    // C/D layout (m89): col = lane&15 (n), row = (lane>>4)*4 + reg (m).
#pragma unroll
    for (int mi = 0; mi < 8; ++mi) {
#pragma unroll
        for (int r = 0; r < 4; ++r) {
            float v0 = acc[mi][0][r], v1 = acc[mi][1][r];
            float v2 = acc[mi][2][r], v3 = acc[mi][3][r];
            float mx = fmaxf(fmaxf(v0, v1), fmaxf(v2, v3));
#pragma unroll
            for (int off = 8; off > 0; off >>= 1)
                mx = fmaxf(mx, __shfl_xor(mx, off, 64));
            float s = expf(v0 - mx) + expf(v1 - mx) + expf(v2 - mx) + expf(v3 - mx);
#pragma unroll
            for (int off = 8; off > 0; off >>= 1)
                s += __shfl_xor(s, off, 64);
            if (m16 == 0) {
                const int row = wm + mi * 16 + g * 4 + r;
                redm[wave & 3][row] = mx;
                reds[wave & 3][row] = s;
            }
        }
    }
    __syncthreads();

    // combine the four 64-col quarters, write partials [nb][m]
    if (tid < 256) {
        const float g0 = redm[0][tid], g1 = redm[1][tid];
        const float g2 = redm[2][tid], g3 = redm[3][tid];
        const float gm = fmaxf(fmaxf(g0, g1), fmaxf(g2, g3));
        const float s  = reds[0][tid] * expf(g0 - gm) + reds[1][tid] * expf(g1 - gm)
                       + reds[2][tid] * expf(g2 - gm) + reds[3][tid] * expf(g3 - gm);
        const size_t idx = (size_t)blockIdx.y * M_TOK + (m0 + tid);
        pmax[idx] = gm;
        psum[idx] = s;
    }
}

#undef BODY
#undef STAGE_A_
#undef STAGE_B_

// ---------------------------------------------------------------------------
// Fallback fp32 GEMM+LSE (R1, passing) — used only if ws_size is too small
// ---------------------------------------------------------------------------
__global__ __launch_bounds__(256)
void gemm_lse_kernel(const float* __restrict__ A, const float* __restrict__ B,
                     float* __restrict__ pmax, float* __restrict__ psum)
{
    constexpr int BK = 16, PAD = 4;
    __shared__ float As[BK][128 + PAD];
    __shared__ float Bs[BK][128 + PAD];

    const int tid = threadIdx.x;
    const int tx  = tid & 15;
    const int ty  = tid >> 4;
    const int m0  = blockIdx.x * 128;
    const int n0  = blockIdx.y * 128;
    const int r0  = tid >> 2;
    const int c0  = tid & 3;
    const float* Ap0 = A + (size_t)(m0 + r0)      * K_H + c0 * 4;
    const float* Ap1 = A + (size_t)(m0 + r0 + 64) * K_H + c0 * 4;
    const float* Bp0 = B + (size_t)(n0 + r0)      * K_H + c0 * 4;
    const float* Bp1 = B + (size_t)(n0 + r0 + 64) * K_H + c0 * 4;

    float acc[8][8];
#pragma unroll
    for (int i = 0; i < 8; ++i)
#pragma unroll
        for (int j = 0; j < 8; ++j) acc[i][j] = 0.0f;

    float4 a0 = *(const float4*)(Ap0);
    float4 a1 = *(const float4*)(Ap1);
    float4 b0 = *(const float4*)(Bp0);
    float4 b1 = *(const float4*)(Bp1);

    for (int kt = 0; kt < K_H; kt += BK) {
        const int kc = c0 * 4;
        As[kc + 0][r0] = a0.x; As[kc + 1][r0] = a0.y; As[kc + 2][r0] = a0.z; As[kc + 3][r0] = a0.w;
        As[kc + 0][r0 + 64] = a1.x; As[kc + 1][r0 + 64] = a1.y; As[kc + 2][r0 + 64] = a1.z; As[kc + 3][r0 + 64] = a1.w;
        Bs[kc + 0][r0] = b0.x; Bs[kc + 1][r0] = b0.y; Bs[kc + 2][r0] = b0.z; Bs[kc + 3][r0] = b0.w;
        Bs[kc + 0][r0 + 64] = b1.x; Bs[kc + 1][r0 + 64] = b1.y; Bs[kc + 2][r0 + 64] = b1.z; Bs[kc + 3][r0 + 64] = b1.w;
        __syncthreads();
        if (kt + BK < K_H) {
            a0 = *(const float4*)(Ap0 + kt + BK);
            a1 = *(const float4*)(Ap1 + kt + BK);
            b0 = *(const float4*)(Bp0 + kt + BK);
            b1 = *(const float4*)(Bp1 + kt + BK);
        }
#pragma unroll
        for (int kk = 0; kk < BK; ++kk) {
            const float4 va0 = *(const float4*)&As[kk][ty * 8];
            const float4 va1 = *(const float4*)&As[kk][ty * 8 + 4];
            const float4 vb0 = *(const float4*)&Bs[kk][tx * 8];
            const float4 vb1 = *(const float4*)&Bs[kk][tx * 8 + 4];
            float av[8] = {va0.x, va0.y, va0.z, va0.w, va1.x, va1.y, va1.z, va1.w};
            float bv[8] = {vb0.x, vb0.y, vb0.z, vb0.w, vb1.x, vb1.y, vb1.z, vb1.w};
#pragma unroll
            for (int i = 0; i < 8; ++i)
#pragma unroll
                for (int j = 0; j < 8; ++j)
                    acc[i][j] = fmaf(av[i], bv[j], acc[i][j]);
        }
        __syncthreads();
    }

#pragma unroll
    for (int i = 0; i < 8; ++i) {
        float mx = acc[i][0];
#pragma unroll
        for (int j = 1; j < 8; ++j) mx = fmaxf(mx, acc[i][j]);
        for (int off = 8; off > 0; off >>= 1)
            mx = fmaxf(mx, __shfl_xor(mx, off, 64));
        float s = 0.0f;
#pragma unroll
        for (int j = 0; j < 8; ++j) s += expf(acc[i][j] - mx);
        for (int off = 8; off > 0; off >>= 1)
            s += __shfl_xor(s, off, 64);
        if (tx == 0) {
            const size_t idx = (size_t)blockIdx.y * M_TOK + (m0 + ty * 8 + i);
            pmax[idx] = mx;
            psum[idx] = s;
        }
    }
}

// ---------------------------------------------------------------------------
// Per-token target logit: tdot[m] = dot(x[m,:], W[target[m],:])  (exact fp32)
// ---------------------------------------------------------------------------
__global__ __launch_bounds__(256)
void tdot_kernel(const float* __restrict__ x, const float* __restrict__ w,
                 const int* __restrict__ tgt, float* __restrict__ tdot)
{
    const int m = blockIdx.x;
    const int lbl = tgt[m];
    const int label = (lbl == IGNORE_IDX) ? 0 : lbl;

    const float4* xr = (const float4*)(x + (size_t)m * K_H);
    const float4* wr = (const float4*)(w + (size_t)label * K_H);
    float s = 0.0f;
    for (int i = threadIdx.x; i < K_H / 4; i += 256) {
        const float4 a = xr[i];
        const float4 b = wr[i];
        s += a.x * b.x + a.y * b.y + a.z * b.z + a.w * b.w;
    }
    __shared__ float red[256];
    red[threadIdx.x] = s;
    __syncthreads();
    for (int st = 128; st > 0; st >>= 1) {
        if (threadIdx.x < st) red[threadIdx.x] += red[threadIdx.x + st];
        __syncthreads();
    }
    if (threadIdx.x == 0) tdot[m] = red[0];
}

// ---------------------------------------------------------------------------
// Per-batch-row average of per-token logps (double online-softmax combine)
// ---------------------------------------------------------------------------
__global__ __launch_bounds__(256)
void finalize_kernel(const float* __restrict__ pmax, const float* __restrict__ psum,
                     const float* __restrict__ tdot, const int* __restrict__ tgt,
                     double* __restrict__ avg_out, int nblk)
{
    const int b = blockIdx.x;
    double lsum = 0.0, lcnt = 0.0;

    for (int t = threadIdx.x; t < T_SEQ; t += 256) {
        const int m = b * T_SEQ + t;
        const int lbl = tgt[m];
        if (lbl != IGNORE_IDX) {
            float gmax = -INFINITY;
            for (int nb = 0; nb < nblk; ++nb)
                gmax = fmaxf(gmax, pmax[(size_t)nb * M_TOK + m]);
            double s = 0.0;
            for (int nb = 0; nb < nblk; ++nb) {
                const size_t idx = (size_t)nb * M_TOK + m;
                s += (double)psum[idx] * exp((double)pmax[idx] - (double)gmax);
            }
            const double lse = (double)gmax + log(s);
            lsum += (double)tdot[m] - lse;
            lcnt += 1.0;
        }
    }

    __shared__ double rs[256];
    __shared__ double rc[256];
    rs[threadIdx.x] = lsum;
    rc[threadIdx.x] = lcnt;
    __syncthreads();
    for (int st = 128; st > 0; st >>= 1) {
        if (threadIdx.x < st) {
            rs[threadIdx.x] += rs[threadIdx.x + st];
            rc[threadIdx.x] += rc[threadIdx.x + st];
        }
        __syncthreads();
    }
    if (threadIdx.x == 0) avg_out[b] = rs[0] / rc[0];
}

// ---------------------------------------------------------------------------
// Deterministic final scalar
// ---------------------------------------------------------------------------
__global__ void loss_kernel(const double* __restrict__ avg, float* __restrict__ out)
{
    if (threadIdx.x == 0 && blockIdx.x == 0) {
        double acc = 0.0;
        for (int i = 0; i < NPAIRS; ++i) acc += avg[i] - avg[i + NPAIRS];
        out[0] = (float)(-(double)BETA * acc / (double)NPAIRS);
    }
}

// ---------------------------------------------------------------------------
extern "C" void kernel_launch(void* const* d_in, const int* in_sizes, int n_in,
                              void* d_out, int out_size, void* d_ws, size_t ws_size,
                              hipStream_t stream)
{
    const float* x = (const float*)d_in[0];          // [8,512,4096] fp32
    const float* w = (const float*)d_in[1];          // [32000,4096] fp32
    const int* tgt = (const int*)d_in[2];            // [8,512] int32

    const size_t xplane = (size_t)M_TOK * K_H;       // 16,777,216 halves
    const size_t wplane = (size_t)V_N * K_H;         // 131,072,000 halves

    // fast-path workspace layout
    _Float16* xh = (_Float16*)d_ws;
    _Float16* xl = xh + xplane;
    _Float16* wh = xl + xplane;
    _Float16* wl = wh + wplane;
    float* pmaxF = (float*)(wl + wplane);
    float* psumF = pmaxF + (size_t)NBLK_M * M_TOK;
    float* tdotF = psumF + (size_t)NBLK_M * M_TOK;
    double* avgF = (double*)(tdotF + M_TOK);
    const size_t need = (size_t)((char*)(avgF + 8) - (char*)d_ws);

    if (ws_size >= need) {
        // convert planes
        const int xn4 = (int)(xplane / 4);
        const int wn4 = (int)(wplane / 4);
        convert_kernel<<<(xn4 + 255) / 256, 256, 0, stream>>>(x, xh, xl, xn4);
        convert_kernel<<<(wn4 + 255) / 256, 256, 0, stream>>>(w, wh, wl, wn4);

        dim3 grid(M_TOK / 256, V_N / 256);   // (16, 125), m fastest
        gemm_mfma_lse256<<<grid, 512, 0, stream>>>(xh, xl, wh, wl, pmaxF, psumF);
        tdot_kernel<<<M_TOK, 256, 0, stream>>>(x, w, tgt, tdotF);
        finalize_kernel<<<8, 256, 0, stream>>>(pmaxF, psumF, tdotF, tgt, avgF, NBLK_M);
        loss_kernel<<<1, 64, 0, stream>>>(avgF, (float*)d_out);
    } else {
        // fallback: fp32 pipeline (needs ~8.2 MB)
        float* pmax = (float*)d_ws;
        float* psum = pmax + (size_t)NBLK_F * M_TOK;
        float* tdot = psum + (size_t)NBLK_F * M_TOK;
        double* avg = (double*)(tdot + M_TOK);
        dim3 grid(M_TOK / 128, V_N / 128);
        gemm_lse_kernel<<<grid, 256, 0, stream>>>(x, w, pmax, psum);
        tdot_kernel<<<M_TOK, 256, 0, stream>>>(x, w, tgt, tdot);
        finalize_kernel<<<8, 256, 0, stream>>>(pmax, psum, tdot, tgt, avg, NBLK_F);
        loss_kernel<<<1, 64, 0, stream>>>(avg, (float*)d_out);
    }
}

// Round 2
// 2018.449 us; speedup vs baseline: 1.9970x; 1.9970x over previous
//
#include <hip/hip_runtime.h>
#include <cmath>

// Problem constants (from reference)
constexpr int K_H   = 4096;    // hidden
constexpr int V_N   = 32000;   // vocab
constexpr int M_TOK = 4096;    // 8 * 512 tokens
constexpr int T_SEQ = 512;
constexpr int NPAIRS = 4;
constexpr float BETA = 0.1f;
constexpr int IGNORE_IDX = -100;   // target arrives as int32 from the harness

constexpr int NBLK = V_N / 128;   // 250 n-tiles

typedef _Float16 h8 __attribute__((ext_vector_type(8)));
typedef _Float16 h4 __attribute__((ext_vector_type(4)));
typedef float    f4 __attribute__((ext_vector_type(4)));

// ---------------------------------------------------------------------------
// async global->LDS 16B (wave-uniform LDS base + lane*16)
// ---------------------------------------------------------------------------
__device__ __forceinline__ void async_copy16(void* lds, const void* g) {
    __builtin_amdgcn_global_load_lds(
        (const __attribute__((address_space(1))) unsigned int*)g,
        (__attribute__((address_space(3))) unsigned int*)lds, 16, 0, 0);
}

// ---------------------------------------------------------------------------
// fp32 -> f16 (round-to-nearest) plane conversion, float4-vectorized
// ---------------------------------------------------------------------------
__global__ __launch_bounds__(256)
void convert_hi_kernel(const float* __restrict__ src, _Float16* __restrict__ hi, int n4)
{
    const int i = blockIdx.x * 256 + threadIdx.x;
    if (i >= n4) return;
    const float4 v = ((const float4*)src)[i];
    h4 h;
    h.x = (_Float16)v.x;
    h.y = (_Float16)v.y;
    h.z = (_Float16)v.z;
    h.w = (_Float16)v.w;
    ((h4*)hi)[i] = h;
}

// ---------------------------------------------------------------------------
// MFMA f16 GEMM + fused per-tile row max / sum(exp).
// A plane xh [M_TOK,K_H]; B plane wh [V_N,K_H]  (f16 round of fp32).
// Precision: per-logit error ~2.8e-4 std; through softmax-weighted lse this
// is ~2.6e-6/token; target logit (tdot) stays exact fp32; final scalar error
// ~1e-7 after 512-token + 4-pair averaging. MFMA accumulation is fp32.
//
// 128x128 tile, BK=64, 4 waves each 64x64 (4x4 of 16x16x32 f16 MFMA).
// LDS staged via global_load_lds(16B) with XOR-octet swizzle:
//   slot s of row r holds k-octet o = s ^ (r&7)  -> conflict-free reads
//   with tight (unpadded) 64-half rows.
// 36 KB LDS/block -> 4 blocks/CU (16 waves/CU) for inter-block overlap.
// ---------------------------------------------------------------------------
__global__ __launch_bounds__(256, 4)
void gemm_mfma_lse(const _Float16* __restrict__ xh, const _Float16* __restrict__ wh,
                   float* __restrict__ pmax, float* __restrict__ psum)
{
    __shared__ _Float16 Ah[128 * 64];
    __shared__ _Float16 Bh[128 * 64];
    __shared__ float redm[2][128];
    __shared__ float reds[2][128];

    const int tid  = threadIdx.x;
    const int wave = tid >> 6;
    const int lane = tid & 63;
    const int g    = lane >> 4;   // k-octet group for fragments
    const int m16  = lane & 15;

    const int m0 = blockIdx.x * 128;   // m fastest in grid -> W tile reuse
    const int n0 = blockIdx.y * 128;
    const int wm = (wave >> 1) * 64;
    const int wn = (wave & 1) * 64;

    // --- staging geometry -------------------------------------------------
    // wave handles tile rows [wave*32, wave*32+32) per plane, 4 instrs x 8 rows.
    // lane l -> row offset l>>3, slot l&7; fetch octet o = (l&7) ^ (l>>3).
    const int lrow = lane >> 3;
    const int oswz = (lane & 7) ^ lrow;
    const int rbase = wave * 32;

    const _Float16* pAh = xh + (size_t)(m0 + rbase + lrow) * K_H + oswz * 8;
    const _Float16* pBh = wh + (size_t)(n0 + rbase + lrow) * K_H + oswz * 8;

    f4 acc[4][4];
#pragma unroll
    for (int i = 0; i < 4; ++i)
#pragma unroll
        for (int j = 0; j < 4; ++j) acc[i][j] = (f4){0.f, 0.f, 0.f, 0.f};

    for (int kt = 0; kt < K_H; kt += 64) {
        __syncthreads();   // LDS reuse: previous chunk's reads complete
#pragma unroll
        for (int i = 0; i < 4; ++i) {
            const size_t go = (size_t)(i * 8) * K_H + kt;
            const int    lo = (rbase + i * 8) * 64;   // halves
            async_copy16(&Ah[lo], pAh + go);
            async_copy16(&Bh[lo], pBh + go);
        }
        __syncthreads();   // drains vmcnt -> LDS valid

#pragma unroll
        for (int ks = 0; ks < 2; ++ks) {
            h8 ahf[4], bhf[4];
#pragma unroll
            for (int t = 0; t < 4; ++t) {
                const int arow = wm + t * 16 + m16;
                const int aoct = (ks * 4 + g) ^ (arow & 7);
                const int aoff = arow * 64 + aoct * 8;
                ahf[t] = *(const h8*)&Ah[aoff];
                const int brow = wn + t * 16 + m16;
                const int boct = (ks * 4 + g) ^ (brow & 7);
                const int boff = brow * 64 + boct * 8;
                bhf[t] = *(const h8*)&Bh[boff];
            }
#pragma unroll
            for (int mi = 0; mi < 4; ++mi)
#pragma unroll
                for (int nj = 0; nj < 4; ++nj)
                    acc[mi][nj] = __builtin_amdgcn_mfma_f32_16x16x32_f16(ahf[mi], bhf[nj], acc[mi][nj], 0, 0, 0);
        }
    }

    // --- epilogue: per-row (M) max & sum(exp) over this wave's 64 cols ----
    // C/D layout (m89): col = lane&15 (n), row = (lane>>4)*4 + reg (m).
    // Row-mates = 16 consecutive lanes of quarter g -> xor-shuffle width 16.
#pragma unroll
    for (int mi = 0; mi < 4; ++mi) {
#pragma unroll
        for (int r = 0; r < 4; ++r) {
            float v0 = acc[mi][0][r], v1 = acc[mi][1][r];
            float v2 = acc[mi][2][r], v3 = acc[mi][3][r];
            float mx = fmaxf(fmaxf(v0, v1), fmaxf(v2, v3));
#pragma unroll
            for (int off = 8; off > 0; off >>= 1)
                mx = fmaxf(mx, __shfl_xor(mx, off, 64));
            float s = expf(v0 - mx) + expf(v1 - mx) + expf(v2 - mx) + expf(v3 - mx);
#pragma unroll
            for (int off = 8; off > 0; off >>= 1)
                s += __shfl_xor(s, off, 64);
            if (m16 == 0) {
                const int row = wm + mi * 16 + g * 4 + r;
                redm[wave & 1][row] = mx;
                reds[wave & 1][row] = s;
            }
        }
    }
    __syncthreads();

    // combine the two 64-col halves, write partials [nb][m]
    if (tid < 128) {
        const float m0v = redm[0][tid], m1v = redm[1][tid];
        const float mx = fmaxf(m0v, m1v);
        const float s  = reds[0][tid] * expf(m0v - mx) + reds[1][tid] * expf(m1v - mx);
        const size_t idx = (size_t)blockIdx.y * M_TOK + (m0 + tid);
        pmax[idx] = mx;
        psum[idx] = s;
    }
}

// ---------------------------------------------------------------------------
// Fallback fp32 GEMM+LSE (R1, passing) — used only if ws_size is too small
// ---------------------------------------------------------------------------
__global__ __launch_bounds__(256)
void gemm_lse_kernel(const float* __restrict__ A, const float* __restrict__ B,
                     float* __restrict__ pmax, float* __restrict__ psum)
{
    constexpr int BK = 16, PAD = 4;
    __shared__ float As[BK][128 + PAD];
    __shared__ float Bs[BK][128 + PAD];

    const int tid = threadIdx.x;
    const int tx  = tid & 15;
    const int ty  = tid >> 4;
    const int m0  = blockIdx.x * 128;
    const int n0  = blockIdx.y * 128;
    const int r0  = tid >> 2;
    const int c0  = tid & 3;
    const float* Ap0 = A + (size_t)(m0 + r0)      * K_H + c0 * 4;
    const float* Ap1 = A + (size_t)(m0 + r0 + 64) * K_H + c0 * 4;
    const float* Bp0 = B + (size_t)(n0 + r0)      * K_H + c0 * 4;
    const float* Bp1 = B + (size_t)(n0 + r0 + 64) * K_H + c0 * 4;

    float acc[8][8];
#pragma unroll
    for (int i = 0; i < 8; ++i)
#pragma unroll
        for (int j = 0; j < 8; ++j) acc[i][j] = 0.0f;

    float4 a0 = *(const float4*)(Ap0);
    float4 a1 = *(const float4*)(Ap1);
    float4 b0 = *(const float4*)(Bp0);
    float4 b1 = *(const float4*)(Bp1);

    for (int kt = 0; kt < K_H; kt += BK) {
        const int kc = c0 * 4;
        As[kc + 0][r0] = a0.x; As[kc + 1][r0] = a0.y; As[kc + 2][r0] = a0.z; As[kc + 3][r0] = a0.w;
        As[kc + 0][r0 + 64] = a1.x; As[kc + 1][r0 + 64] = a1.y; As[kc + 2][r0 + 64] = a1.z; As[kc + 3][r0 + 64] = a1.w;
        Bs[kc + 0][r0] = b0.x; Bs[kc + 1][r0] = b0.y; Bs[kc + 2][r0] = b0.z; Bs[kc + 3][r0] = b0.w;
        Bs[kc + 0][r0 + 64] = b1.x; Bs[kc + 1][r0 + 64] = b1.y; Bs[kc + 2][r0 + 64] = b1.z; Bs[kc + 3][r0 + 64] = b1.w;
        __syncthreads();
        if (kt + BK < K_H) {
            a0 = *(const float4*)(Ap0 + kt + BK);
            a1 = *(const float4*)(Ap1 + kt + BK);
            b0 = *(const float4*)(Bp0 + kt + BK);
            b1 = *(const float4*)(Bp1 + kt + BK);
        }
#pragma unroll
        for (int kk = 0; kk < BK; ++kk) {
            const float4 va0 = *(const float4*)&As[kk][ty * 8];
            const float4 va1 = *(const float4*)&As[kk][ty * 8 + 4];
            const float4 vb0 = *(const float4*)&Bs[kk][tx * 8];
            const float4 vb1 = *(const float4*)&Bs[kk][tx * 8 + 4];
            float av[8] = {va0.x, va0.y, va0.z, va0.w, va1.x, va1.y, va1.z, va1.w};
            float bv[8] = {vb0.x, vb0.y, vb0.z, vb0.w, vb1.x, vb1.y, vb1.z, vb1.w};
#pragma unroll
            for (int i = 0; i < 8; ++i)
#pragma unroll
                for (int j = 0; j < 8; ++j)
                    acc[i][j] = fmaf(av[i], bv[j], acc[i][j]);
        }
        __syncthreads();
    }

#pragma unroll
    for (int i = 0; i < 8; ++i) {
        float mx = acc[i][0];
#pragma unroll
        for (int j = 1; j < 8; ++j) mx = fmaxf(mx, acc[i][j]);
        for (int off = 8; off > 0; off >>= 1)
            mx = fmaxf(mx, __shfl_xor(mx, off, 64));
        float s = 0.0f;
#pragma unroll
        for (int j = 0; j < 8; ++j) s += expf(acc[i][j] - mx);
        for (int off = 8; off > 0; off >>= 1)
            s += __shfl_xor(s, off, 64);
        if (tx == 0) {
            const size_t idx = (size_t)blockIdx.y * M_TOK + (m0 + ty * 8 + i);
            pmax[idx] = mx;
            psum[idx] = s;
        }
    }
}

// ---------------------------------------------------------------------------
// Per-token target logit: tdot[m] = dot(x[m,:], W[target[m],:])  (exact fp32)
// ---------------------------------------------------------------------------
__global__ __launch_bounds__(256)
void tdot_kernel(const float* __restrict__ x, const float* __restrict__ w,
                 const int* __restrict__ tgt, float* __restrict__ tdot)
{
    const int m = blockIdx.x;
    const int lbl = tgt[m];
    const int label = (lbl == IGNORE_IDX) ? 0 : lbl;

    const float4* xr = (const float4*)(x + (size_t)m * K_H);
    const float4* wr = (const float4*)(w + (size_t)label * K_H);
    float s = 0.0f;
    for (int i = threadIdx.x; i < K_H / 4; i += 256) {
        const float4 a = xr[i];
        const float4 b = wr[i];
        s += a.x * b.x + a.y * b.y + a.z * b.z + a.w * b.w;
    }
    __shared__ float red[256];
    red[threadIdx.x] = s;
    __syncthreads();
    for (int st = 128; st > 0; st >>= 1) {
        if (threadIdx.x < st) red[threadIdx.x] += red[threadIdx.x + st];
        __syncthreads();
    }
    if (threadIdx.x == 0) tdot[m] = red[0];
}

// ---------------------------------------------------------------------------
// Per-batch-row average of per-token logps (double online-softmax combine)
// ---------------------------------------------------------------------------
__global__ __launch_bounds__(256)
void finalize_kernel(const float* __restrict__ pmax, const float* __restrict__ psum,
                     const float* __restrict__ tdot, const int* __restrict__ tgt,
                     double* __restrict__ avg_out)
{
    const int b = blockIdx.x;
    double lsum = 0.0, lcnt = 0.0;

    for (int t = threadIdx.x; t < T_SEQ; t += 256) {
        const int m = b * T_SEQ + t;
        const int lbl = tgt[m];
        if (lbl != IGNORE_IDX) {
            float gmax = -INFINITY;
            for (int nb = 0; nb < NBLK; ++nb)
                gmax = fmaxf(gmax, pmax[(size_t)nb * M_TOK + m]);
            double s = 0.0;
            for (int nb = 0; nb < NBLK; ++nb) {
                const size_t idx = (size_t)nb * M_TOK + m;
                s += (double)psum[idx] * exp((double)pmax[idx] - (double)gmax);
            }
            const double lse = (double)gmax + log(s);
            lsum += (double)tdot[m] - lse;
            lcnt += 1.0;
        }
    }

    __shared__ double rs[256];
    __shared__ double rc[256];
    rs[threadIdx.x] = lsum;
    rc[threadIdx.x] = lcnt;
    __syncthreads();
    for (int st = 128; st > 0; st >>= 1) {
        if (threadIdx.x < st) {
            rs[threadIdx.x] += rs[threadIdx.x + st];
            rc[threadIdx.x] += rc[threadIdx.x + st];
        }
        __syncthreads();
    }
    if (threadIdx.x == 0) avg_out[b] = rs[0] / rc[0];
}

// ---------------------------------------------------------------------------
// Deterministic final scalar
// ---------------------------------------------------------------------------
__global__ void loss_kernel(const double* __restrict__ avg, float* __restrict__ out)
{
    if (threadIdx.x == 0 && blockIdx.x == 0) {
        double acc = 0.0;
        for (int i = 0; i < NPAIRS; ++i) acc += avg[i] - avg[i + NPAIRS];
        out[0] = (float)(-(double)BETA * acc / (double)NPAIRS);
    }
}

// ---------------------------------------------------------------------------
extern "C" void kernel_launch(void* const* d_in, const int* in_sizes, int n_in,
                              void* d_out, int out_size, void* d_ws, size_t ws_size,
                              hipStream_t stream)
{
    const float* x = (const float*)d_in[0];          // [8,512,4096] fp32
    const float* w = (const float*)d_in[1];          // [32000,4096] fp32
    const int* tgt = (const int*)d_in[2];            // [8,512] int32

    const size_t xplane = (size_t)M_TOK * K_H;       // 16,777,216 halves
    const size_t wplane = (size_t)V_N * K_H;         // 131,072,000 halves

    // fast-path workspace layout (f16 hi planes only)
    _Float16* xh = (_Float16*)d_ws;
    _Float16* wh = xh + xplane;
    float* pmaxF = (float*)(wh + wplane);
    float* psumF = pmaxF + (size_t)NBLK * M_TOK;
    float* tdotF = psumF + (size_t)NBLK * M_TOK;
    double* avgF = (double*)(tdotF + M_TOK);
    const size_t need = (size_t)((char*)(avgF + 8) - (char*)d_ws);

    if (ws_size >= need) {
        // convert planes (hi only)
        const int xn4 = (int)(xplane / 4);
        const int wn4 = (int)(wplane / 4);
        convert_hi_kernel<<<(xn4 + 255) / 256, 256, 0, stream>>>(x, xh, xn4);
        convert_hi_kernel<<<(wn4 + 255) / 256, 256, 0, stream>>>(w, wh, wn4);

        dim3 grid(M_TOK / 128, V_N / 128);   // (32, 250), m fastest
        gemm_mfma_lse<<<grid, 256, 0, stream>>>(xh, wh, pmaxF, psumF);
        tdot_kernel<<<M_TOK, 256, 0, stream>>>(x, w, tgt, tdotF);
        finalize_kernel<<<8, 256, 0, stream>>>(pmaxF, psumF, tdotF, tgt, avgF);
        loss_kernel<<<1, 64, 0, stream>>>(avgF, (float*)d_out);
    } else {
        // fallback: fp32 pipeline (needs ~8.2 MB)
        float* pmax = (float*)d_ws;
        float* psum = pmax + (size_t)NBLK * M_TOK;
        float* tdot = psum + (size_t)NBLK * M_TOK;
        double* avg = (double*)(tdot + M_TOK);
        dim3 grid(M_TOK / 128, V_N / 128);
        gemm_lse_kernel<<<grid, 256, 0, stream>>>(x, w, pmax, psum);
        tdot_kernel<<<M_TOK, 256, 0, stream>>>(x, w, tgt, tdot);
        finalize_kernel<<<8, 256, 0, stream>>>(pmax, psum, tdot, tgt, avg);
        loss_kernel<<<1, 64, 0, stream>>>(avg, (float*)d_out);
    }
}

// Round 3
// 1799.575 us; speedup vs baseline: 2.2399x; 1.1216x over previous
//
#include <hip/hip_runtime.h>
#include <cmath>

// Problem constants (from reference)
constexpr int K_H   = 4096;    // hidden
constexpr int V_N   = 32000;   // vocab
constexpr int M_TOK = 4096;    // 8 * 512 tokens
constexpr int T_SEQ = 512;
constexpr int NPAIRS = 4;
constexpr float BETA = 0.1f;
constexpr int IGNORE_IDX = -100;   // target arrives as int32 from the harness

constexpr int NBLK_M = V_N / 256;  // 125 n-tiles (mfma path)
constexpr int NBLK_F = V_N / 128;  // 250 n-tiles (fp32 fallback)

typedef _Float16 h8 __attribute__((ext_vector_type(8)));
typedef _Float16 h4 __attribute__((ext_vector_type(4)));
typedef float    f4 __attribute__((ext_vector_type(4)));

// ---------------------------------------------------------------------------
// async global->LDS 16B (wave-uniform LDS base + lane*16)
// ---------------------------------------------------------------------------
__device__ __forceinline__ void async_copy16(void* lds, const void* g) {
    __builtin_amdgcn_global_load_lds(
        (const __attribute__((address_space(1))) unsigned int*)g,
        (__attribute__((address_space(3))) unsigned int*)lds, 16, 0, 0);
}

// ---------------------------------------------------------------------------
// fp32 -> f16 conversion for both planes in ONE launch (w first, then x)
// ---------------------------------------------------------------------------
__global__ __launch_bounds__(256)
void convert_both_kernel(const float* __restrict__ x, const float* __restrict__ w,
                         _Float16* __restrict__ xh, _Float16* __restrict__ wh,
                         int xn4, int wn4)
{
    int i = blockIdx.x * 256 + threadIdx.x;
    const float4* src;
    h4* dst;
    if (i < wn4) {
        src = (const float4*)w; dst = (h4*)wh;
    } else {
        i -= wn4;
        if (i >= xn4) return;
        src = (const float4*)x; dst = (h4*)xh;
    }
    const float4 v = src[i];
    h4 h;
    h.x = (_Float16)v.x;
    h.y = (_Float16)v.y;
    h.z = (_Float16)v.z;
    h.w = (_Float16)v.w;
    dst[i] = h;
}

// ---------------------------------------------------------------------------
// 256x256-tile f16 MFMA GEMM + fused per-row max / sum(exp).
// Faithful port of the verified 8-phase counted-vmcnt schedule (m201):
//   BK=64, 8 waves (2M x 4N), per-wave 128x64 output, 2 K-tiles/iteration,
//   8 phases/iter, each phase: {ds_read subtile, stage 1 half-tile
//   (2 x global_load_lds), barrier, lgkmcnt(0), setprio(1) 16 MFMA
//   setprio(0), barrier}; s_waitcnt vmcnt(4) only at phases 4 and 8.
//
// LDS per plane per buffer: 256 rows x 64 halves, XOR-octet swizzle:
//   slot s of row r holds k-octet o = s ^ (r&7) (conflict-free ds_read_b128,
//   measured 0 conflicts in R2). global_load_lds writes linearly; the
//   per-lane GLOBAL source carries the inverse swizzle (rule #21).
//
// Staging schedule (iter i, tiles t=2i from buf0, t+1 from buf1):
//   P0: A0(t+1)->buf1   P1: A1(t+1)->buf1   (buf1-A last read prev P6)
//   P2: B0(t+2)->buf0   P3: B1(t+2)->buf0   (buf0-B last read P1)
//   P4: A0(t+2)->buf0   P5: A1(t+2)->buf0   (buf0-A last read P2)
//   P6: B0(t+3)->buf1   P7: B1(t+3)->buf1   (buf1-B last read P5)
// vmcnt(4) at P3-end: retires through A1(t+1) (4 newer: B(t+2));
// vmcnt(4) at P7-end: retires through A1(t+2) (4 newer: B(t+3)).
// ---------------------------------------------------------------------------

#define VMW(N)  asm volatile("s_waitcnt vmcnt(" #N ")" ::: "memory")
#define NOPS    ((void)0)

#define STAGE(BUF, PLANE, SRC, HALF, KT) do { \
    async_copy16(&LB[BUF][PLANE][(HALF)*8192 + wave*1024],       (SRC) + (size_t)((HALF)*128 + wave*16 + 0) * K_H + (KT)); \
    async_copy16(&LB[BUF][PLANE][(HALF)*8192 + wave*1024 + 512], (SRC) + (size_t)((HALF)*128 + wave*16 + 8) * K_H + (KT)); \
} while (0)

#define LOAD_A(BUF, HALF) do { \
    const _Float16* Ap_ = &LB[BUF][0][0]; \
    _Pragma("unroll") \
    for (int i_ = 0; i_ < 4; ++i_) { \
        aF[i_][0] = *(const h8*)&Ap_[arow0 + ((HALF)*4 + i_)*1024 + aslot0]; \
        aF[i_][1] = *(const h8*)&Ap_[arow0 + ((HALF)*4 + i_)*1024 + aslot1]; \
    } \
} while (0)

#define LOAD_B(BUF, HN) do { \
    const _Float16* Bp_ = &LB[BUF][1][0]; \
    _Pragma("unroll") \
    for (int j_ = 0; j_ < 2; ++j_) { \
        bF[(HN)*2 + j_][0] = *(const h8*)&Bp_[brow0 + ((HN)*2 + j_)*1024 + aslot0]; \
        bF[(HN)*2 + j_][1] = *(const h8*)&Bp_[brow0 + ((HN)*2 + j_)*1024 + aslot1]; \
    } \
} while (0)

#define MFMA_Q(MH, NH) do { \
    _Pragma("unroll") \
    for (int ks_ = 0; ks_ < 2; ++ks_) \
        _Pragma("unroll") \
        for (int i_ = 0; i_ < 4; ++i_) \
            _Pragma("unroll") \
            for (int j_ = 0; j_ < 2; ++j_) \
                acc[(MH)*4 + i_][(NH)*2 + j_] = __builtin_amdgcn_mfma_f32_16x16x32_f16( \
                    aF[i_][ks_], bF[(NH)*2 + j_][ks_], acc[(MH)*4 + i_][(NH)*2 + j_], 0, 0, 0); \
} while (0)

#define PH_SYNC() do { \
    asm volatile("" ::: "memory"); \
    __builtin_amdgcn_s_barrier(); \
    asm volatile("s_waitcnt lgkmcnt(0)" ::: "memory"); \
    __builtin_amdgcn_sched_barrier(0); \
} while (0)

#define PH_END() do { \
    asm volatile("" ::: "memory"); \
    __builtin_amdgcn_s_barrier(); \
    asm volatile("" ::: "memory"); \
} while (0)

#define KTILE(BUF, S0, S1, S2, S3, VM) do { \
    LOAD_A(BUF, 0); LOAD_B(BUF, 0); \
    S0; \
    PH_SYNC(); \
    __builtin_amdgcn_s_setprio(1); MFMA_Q(0, 0); __builtin_amdgcn_s_setprio(0); \
    PH_END(); \
    LOAD_B(BUF, 1); \
    S1; \
    PH_SYNC(); \
    __builtin_amdgcn_s_setprio(1); MFMA_Q(0, 1); __builtin_amdgcn_s_setprio(0); \
    PH_END(); \
    LOAD_A(BUF, 1); \
    S2; \
    PH_SYNC(); \
    __builtin_amdgcn_s_setprio(1); MFMA_Q(1, 0); __builtin_amdgcn_s_setprio(0); \
    PH_END(); \
    S3; \
    asm volatile("" ::: "memory"); \
    __builtin_amdgcn_s_barrier(); \
    __builtin_amdgcn_s_setprio(1); MFMA_Q(1, 1); __builtin_amdgcn_s_setprio(0); \
    VM; \
    PH_END(); \
} while (0)

__global__ __launch_bounds__(512, 2)
void gemm_mfma_lse(const _Float16* __restrict__ xh, const _Float16* __restrict__ wh,
                   float* __restrict__ pmax, float* __restrict__ psum)
{
    __shared__ _Float16 LB[2][2][256 * 64];   // [buf][plane A=0/B=1], 128 KiB
    __shared__ float redm[4][256];
    __shared__ float reds[4][256];

    const int tid  = threadIdx.x;
    const int wave = tid >> 6;          // 0..7
    const int lane = tid & 63;
    const int g    = lane >> 4;         // k-octet group
    const int m16  = lane & 15;

    const int m0 = blockIdx.x * 256;    // m fastest in grid -> W tile reuse
    const int n0 = blockIdx.y * 256;
    const int wm = (wave >> 2) * 128;   // 0 or 128
    const int wn = (wave & 3) * 64;     // 0,64,128,192

    // staging source geometry (per-lane; inverse of the LDS XOR swizzle)
    const int lrow = lane >> 3;                 // 0..7
    const int oswz = (lane & 7) ^ lrow;         // source octet for slot lane&7
    const _Float16* srcA = xh + (size_t)(m0 + lrow) * K_H + oswz * 8;
    const _Float16* srcB = wh + (size_t)(n0 + lrow) * K_H + oswz * 8;

    // fragment read offsets: row = base + mi*16 + m16, row&7 == m16&7
    const int aslot0 = ((0 + g) ^ (m16 & 7)) * 8;   // ks=0
    const int aslot1 = ((4 + g) ^ (m16 & 7)) * 8;   // ks=1
    const int arow0  = (wm + m16) * 64;
    const int brow0  = (wn + m16) * 64;

    h8 aF[4][2];   // current m-half fragments [mi][ks]
    h8 bF[4][2];   // all n fragments       [nj][ks]
    f4 acc[8][4];
#pragma unroll
    for (int i = 0; i < 8; ++i)
#pragma unroll
        for (int j = 0; j < 4; ++j) acc[i][j] = (f4){0.f, 0.f, 0.f, 0.f};

    // ---- prologue: tile0 (buf0) + B of tile1 (buf1); 12 loads ----
    STAGE(0, 0, srcA, 0, 0);
    STAGE(0, 0, srcA, 1, 0);
    STAGE(0, 1, srcB, 0, 0);
    STAGE(0, 1, srcB, 1, 0);
    STAGE(1, 1, srcB, 0, 64);
    STAGE(1, 1, srcB, 1, 64);
    VMW(4);                                  // tile0's 8 loads retired
    __builtin_amdgcn_s_barrier();
    asm volatile("" ::: "memory");

    // ---- main loop: 31 iterations x 2 K-tiles ----
#pragma clang loop unroll(disable)
    for (int i = 0; i < 31; ++i) {
        const int kA1 = (2 * i + 1) * 64;
        const int kT2 = (2 * i + 2) * 64;
        const int kB3 = (2 * i + 3) * 64;
        KTILE(0,
              STAGE(1, 0, srcA, 0, kA1),
              STAGE(1, 0, srcA, 1, kA1),
              STAGE(0, 1, srcB, 0, kT2),
              STAGE(0, 1, srcB, 1, kT2),
              VMW(4));
        KTILE(1,
              STAGE(0, 0, srcA, 0, kT2),
              STAGE(0, 0, srcA, 1, kT2),
              STAGE(1, 1, srcB, 0, kB3),
              STAGE(1, 1, srcB, 1, kB3),
              VMW(4));
    }
    // ---- peeled last pair: tiles 62, 63 ----
    KTILE(0,
          STAGE(1, 0, srcA, 0, 63 * 64),
          STAGE(1, 0, srcA, 1, 63 * 64),
          NOPS, NOPS, VMW(0));
    KTILE(1, NOPS, NOPS, NOPS, NOPS, NOPS);

    // ---- epilogue: per-row (M) max & sum(exp) over this wave's 64 cols ----
    // C/D layout (m89): col = lane&15 (n), row = (lane>>4)*4 + reg (m).
#pragma unroll
    for (int mi = 0; mi < 8; ++mi) {
#pragma unroll
        for (int r = 0; r < 4; ++r) {
            float v0 = acc[mi][0][r], v1 = acc[mi][1][r];
            float v2 = acc[mi][2][r], v3 = acc[mi][3][r];
            float mx = fmaxf(fmaxf(v0, v1), fmaxf(v2, v3));
#pragma unroll
            for (int off = 8; off > 0; off >>= 1)
                mx = fmaxf(mx, __shfl_xor(mx, off, 64));
            float s = expf(v0 - mx) + expf(v1 - mx) + expf(v2 - mx) + expf(v3 - mx);
#pragma unroll
            for (int off = 8; off > 0; off >>= 1)
                s += __shfl_xor(s, off, 64);
            if (m16 == 0) {
                const int row = wm + mi * 16 + g * 4 + r;
                redm[wave & 3][row] = mx;
                reds[wave & 3][row] = s;
            }
        }
    }
    __syncthreads();

    // combine the four 64-col quarters, write partials [nb][m]
    if (tid < 256) {
        const float g0 = redm[0][tid], g1 = redm[1][tid];
        const float g2 = redm[2][tid], g3 = redm[3][tid];
        const float gm = fmaxf(fmaxf(g0, g1), fmaxf(g2, g3));
        const float s  = reds[0][tid] * expf(g0 - gm) + reds[1][tid] * expf(g1 - gm)
                       + reds[2][tid] * expf(g2 - gm) + reds[3][tid] * expf(g3 - gm);
        const size_t idx = (size_t)blockIdx.y * M_TOK + (m0 + tid);
        pmax[idx] = gm;
        psum[idx] = s;
    }
}

// ---------------------------------------------------------------------------
// Fallback fp32 GEMM+LSE — used only if ws_size is too small
// ---------------------------------------------------------------------------
__global__ __launch_bounds__(256)
void gemm_lse_kernel(const float* __restrict__ A, const float* __restrict__ B,
                     float* __restrict__ pmax, float* __restrict__ psum)
{
    constexpr int BK = 16, PAD = 4;
    __shared__ float As[BK][128 + PAD];
    __shared__ float Bs[BK][128 + PAD];

    const int tid = threadIdx.x;
    const int tx  = tid & 15;
    const int ty  = tid >> 4;
    const int m0  = blockIdx.x * 128;
    const int n0  = blockIdx.y * 128;
    const int r0  = tid >> 2;
    const int c0  = tid & 3;
    const float* Ap0 = A + (size_t)(m0 + r0)      * K_H + c0 * 4;
    const float* Ap1 = A + (size_t)(m0 + r0 + 64) * K_H + c0 * 4;
    const float* Bp0 = B + (size_t)(n0 + r0)      * K_H + c0 * 4;
    const float* Bp1 = B + (size_t)(n0 + r0 + 64) * K_H + c0 * 4;

    float acc[8][8];
#pragma unroll
    for (int i = 0; i < 8; ++i)
#pragma unroll
        for (int j = 0; j < 8; ++j) acc[i][j] = 0.0f;

    float4 a0 = *(const float4*)(Ap0);
    float4 a1 = *(const float4*)(Ap1);
    float4 b0 = *(const float4*)(Bp0);
    float4 b1 = *(const float4*)(Bp1);

    for (int kt = 0; kt < K_H; kt += BK) {
        const int kc = c0 * 4;
        As[kc + 0][r0] = a0.x; As[kc + 1][r0] = a0.y; As[kc + 2][r0] = a0.z; As[kc + 3][r0] = a0.w;
        As[kc + 0][r0 + 64] = a1.x; As[kc + 1][r0 + 64] = a1.y; As[kc + 2][r0 + 64] = a1.z; As[kc + 3][r0 + 64] = a1.w;
        Bs[kc + 0][r0] = b0.x; Bs[kc + 1][r0] = b0.y; Bs[kc + 2][r0] = b0.z; Bs[kc + 3][r0] = b0.w;
        Bs[kc + 0][r0 + 64] = b1.x; Bs[kc + 1][r0 + 64] = b1.y; Bs[kc + 2][r0 + 64] = b1.z; Bs[kc + 3][r0 + 64] = b1.w;
        __syncthreads();
        if (kt + BK < K_H) {
            a0 = *(const float4*)(Ap0 + kt + BK);
            a1 = *(const float4*)(Ap1 + kt + BK);
            b0 = *(const float4*)(Bp0 + kt + BK);
            b1 = *(const float4*)(Bp1 + kt + BK);
        }
#pragma unroll
        for (int kk = 0; kk < BK; ++kk) {
            const float4 va0 = *(const float4*)&As[kk][ty * 8];
            const float4 va1 = *(const float4*)&As[kk][ty * 8 + 4];
            const float4 vb0 = *(const float4*)&Bs[kk][tx * 8];
            const float4 vb1 = *(const float4*)&Bs[kk][tx * 8 + 4];
            float av[8] = {va0.x, va0.y, va0.z, va0.w, va1.x, va1.y, va1.z, va1.w};
            float bv[8] = {vb0.x, vb0.y, vb0.z, vb0.w, vb1.x, vb1.y, vb1.z, vb1.w};
#pragma unroll
            for (int i = 0; i < 8; ++i)
#pragma unroll
                for (int j = 0; j < 8; ++j)
                    acc[i][j] = fmaf(av[i], bv[j], acc[i][j]);
        }
        __syncthreads();
    }

#pragma unroll
    for (int i = 0; i < 8; ++i) {
        float mx = acc[i][0];
#pragma unroll
        for (int j = 1; j < 8; ++j) mx = fmaxf(mx, acc[i][j]);
        for (int off = 8; off > 0; off >>= 1)
            mx = fmaxf(mx, __shfl_xor(mx, off, 64));
        float s = 0.0f;
#pragma unroll
        for (int j = 0; j < 8; ++j) s += expf(acc[i][j] - mx);
        for (int off = 8; off > 0; off >>= 1)
            s += __shfl_xor(s, off, 64);
        if (tx == 0) {
            const size_t idx = (size_t)blockIdx.y * M_TOK + (m0 + ty * 8 + i);
            pmax[idx] = mx;
            psum[idx] = s;
        }
    }
}

// ---------------------------------------------------------------------------
// Per-token target logit: tdot[m] = dot(x[m,:], W[target[m],:])  (exact fp32)
// ---------------------------------------------------------------------------
__global__ __launch_bounds__(256)
void tdot_kernel(const float* __restrict__ x, const float* __restrict__ w,
                 const int* __restrict__ tgt, float* __restrict__ tdot)
{
    const int m = blockIdx.x;
    const int lbl = tgt[m];
    const int label = (lbl == IGNORE_IDX) ? 0 : lbl;

    const float4* xr = (const float4*)(x + (size_t)m * K_H);
    const float4* wr = (const float4*)(w + (size_t)label * K_H);
    float s = 0.0f;
    for (int i = threadIdx.x; i < K_H / 4; i += 256) {
        const float4 a = xr[i];
        const float4 b = wr[i];
        s += a.x * b.x + a.y * b.y + a.z * b.z + a.w * b.w;
    }
    __shared__ float red[256];
    red[threadIdx.x] = s;
    __syncthreads();
    for (int st = 128; st > 0; st >>= 1) {
        if (threadIdx.x < st) red[threadIdx.x] += red[threadIdx.x + st];
        __syncthreads();
    }
    if (threadIdx.x == 0) tdot[m] = red[0];
}

// ---------------------------------------------------------------------------
// Per-token logp partial sums; grid (8 batch-rows, 4 splits) x 128 threads.
// part[(b*4+sb)*2] = sum of (tdot - lse), part[...+1] = token count.
// ---------------------------------------------------------------------------
__global__ __launch_bounds__(128)
void finalize_kernel(const float* __restrict__ pmax, const float* __restrict__ psum,
                     const float* __restrict__ tdot, const int* __restrict__ tgt,
                     double* __restrict__ part, int nblk)
{
    const int b  = blockIdx.x;
    const int sb = blockIdx.y;
    const int t  = sb * 128 + threadIdx.x;
    const int m  = b * T_SEQ + t;

    double lsum = 0.0, lcnt = 0.0;
    const int lbl = tgt[m];
    if (lbl != IGNORE_IDX) {
        float gmax = -INFINITY;
        for (int nb = 0; nb < nblk; ++nb)
            gmax = fmaxf(gmax, pmax[(size_t)nb * M_TOK + m]);
        double s = 0.0;
        for (int nb = 0; nb < nblk; ++nb) {
            const size_t idx = (size_t)nb * M_TOK + m;
            s += (double)psum[idx] * exp((double)pmax[idx] - (double)gmax);
        }
        lsum = (double)tdot[m] - ((double)gmax + log(s));
        lcnt = 1.0;
    }

    __shared__ double rs[128];
    __shared__ double rc[128];
    rs[threadIdx.x] = lsum;
    rc[threadIdx.x] = lcnt;
    __syncthreads();
    for (int st = 64; st > 0; st >>= 1) {
        if (threadIdx.x < st) {
            rs[threadIdx.x] += rs[threadIdx.x + st];
            rc[threadIdx.x] += rc[threadIdx.x + st];
        }
        __syncthreads();
    }
    if (threadIdx.x == 0) {
        part[(size_t)(b * 4 + sb) * 2 + 0] = rs[0];
        part[(size_t)(b * 4 + sb) * 2 + 1] = rc[0];
    }
}

// ---------------------------------------------------------------------------
// Deterministic final scalar from the 32 partials
// ---------------------------------------------------------------------------
__global__ void loss_kernel(const double* __restrict__ part, float* __restrict__ out)
{
    if (threadIdx.x == 0 && blockIdx.x == 0) {
        double acc = 0.0;
        for (int p = 0; p < NPAIRS; ++p) {
            double sc = 0.0, cc = 0.0, sr = 0.0, cr = 0.0;
            for (int sb = 0; sb < 4; ++sb) {
                sc += part[(size_t)(p * 4 + sb) * 2 + 0];
                cc += part[(size_t)(p * 4 + sb) * 2 + 1];
                sr += part[(size_t)((p + NPAIRS) * 4 + sb) * 2 + 0];
                cr += part[(size_t)((p + NPAIRS) * 4 + sb) * 2 + 1];
            }
            acc += sc / cc - sr / cr;
        }
        out[0] = (float)(-(double)BETA * acc / (double)NPAIRS);
    }
}

// ---------------------------------------------------------------------------
extern "C" void kernel_launch(void* const* d_in, const int* in_sizes, int n_in,
                              void* d_out, int out_size, void* d_ws, size_t ws_size,
                              hipStream_t stream)
{
    const float* x = (const float*)d_in[0];          // [8,512,4096] fp32
    const float* w = (const float*)d_in[1];          // [32000,4096] fp32
    const int* tgt = (const int*)d_in[2];            // [8,512] int32

    const size_t xplane = (size_t)M_TOK * K_H;       // 16,777,216 halves
    const size_t wplane = (size_t)V_N * K_H;         // 131,072,000 halves

    // fast-path workspace layout (f16 planes)
    _Float16* xh = (_Float16*)d_ws;
    _Float16* wh = xh + xplane;
    float* pmaxF = (float*)(wh + wplane);
    float* psumF = pmaxF + (size_t)NBLK_M * M_TOK;
    float* tdotF = psumF + (size_t)NBLK_M * M_TOK;
    double* partF = (double*)(tdotF + M_TOK);
    const size_t need = (size_t)((char*)(partF + 64) - (char*)d_ws);

    if (ws_size >= need) {
        const int xn4 = (int)(xplane / 4);
        const int wn4 = (int)(wplane / 4);
        convert_both_kernel<<<(xn4 + wn4 + 255) / 256, 256, 0, stream>>>(x, w, xh, wh, xn4, wn4);

        dim3 grid(M_TOK / 256, V_N / 256);   // (16, 125), m fastest
        gemm_mfma_lse<<<grid, 512, 0, stream>>>(xh, wh, pmaxF, psumF);
        tdot_kernel<<<M_TOK, 256, 0, stream>>>(x, w, tgt, tdotF);
        finalize_kernel<<<dim3(8, 4), 128, 0, stream>>>(pmaxF, psumF, tdotF, tgt, partF, NBLK_M);
        loss_kernel<<<1, 64, 0, stream>>>(partF, (float*)d_out);
    } else {
        // fallback: fp32 pipeline (needs ~8.2 MB)
        float* pmax = (float*)d_ws;
        float* psum = pmax + (size_t)NBLK_F * M_TOK;
        float* tdot = psum + (size_t)NBLK_F * M_TOK;
        double* part = (double*)(tdot + M_TOK);
        dim3 grid(M_TOK / 128, V_N / 128);
        gemm_lse_kernel<<<grid, 256, 0, stream>>>(x, w, pmax, psum);
        tdot_kernel<<<M_TOK, 256, 0, stream>>>(x, w, tgt, tdot);
        finalize_kernel<<<dim3(8, 4), 128, 0, stream>>>(pmax, psum, tdot, tgt, part, NBLK_F);
        loss_kernel<<<1, 64, 0, stream>>>(part, (float*)d_out);
    }
}